// Round 15
// baseline (449.569 us; speedup 1.0000x reference)
//
#include <hip/hip_runtime.h>
#include <hip/hip_bf16.h>
#include <cstdint>
#include <cstddef>

// ---------------------------------------------------------------------------
// SAGE GNN forward, bf16 MFMA 32x32x16, LDS-staged GEMM, BK=64.
//  - GEMM: round-6 schedule + XCD-co-located col-blocks; B direct from global
//    (packed, L2-resident), per-tile B loads hoisted
//  - L4 GEMM: head FUSED into epilogue (LDS transpose + partial 4-class dot);
//    no h4 materialization. Tiny final kernel sums partials + softmax.
//  - L1: linearity swap (raw GEMM then 64-wide fused aggregate)
//  - aggregates: uint4 lanes, 32-edge shfl-broadcast batches
//  - CSR: x8-batched atomics
// ---------------------------------------------------------------------------

typedef short bf16x8 __attribute__((ext_vector_type(8)));   // 8 bf16 = 4 VGPRs
typedef float f32x16 __attribute__((ext_vector_type(16)));

static inline int idiv_up(int a, int b) { return (a + b - 1) / b; }

static __device__ __forceinline__ float bf2f(unsigned short u) {
  union { unsigned int i; float f; } v; v.i = ((unsigned int)u) << 16; return v.f;
}
static __device__ __forceinline__ unsigned short f2bf(float f) {
  union { float f; unsigned int i; } v; v.f = f;
  return (unsigned short)((v.i + 0x7FFFu + ((v.i >> 16) & 1u)) >> 16);  // RNE
}
static __device__ __forceinline__ float lo16(unsigned int u) { return bf2f((unsigned short)(u & 0xffffu)); }
static __device__ __forceinline__ float hi16(unsigned int u) { return bf2f((unsigned short)(u >> 16)); }
static __device__ __forceinline__ unsigned int packbf(float a, float b) {
  return (unsigned int)f2bf(a) | ((unsigned int)f2bf(b) << 16);
}

// async global->LDS, 16B per lane. LDS dest: wave-uniform base + lane*16.
static __device__ __forceinline__ void gl_lds16(const void* g, void* l) {
  typedef __attribute__((address_space(3))) unsigned int lds_u32;
  typedef __attribute__((address_space(1))) const unsigned int glb_u32;
  __builtin_amdgcn_global_load_lds((glb_u32*)(uintptr_t)g,
                                   (lds_u32*)(unsigned int)(uintptr_t)l, 16, 0, 0);
}

// ---------------- CSR build ----------------
// x8 edges per thread (strided): 8 independent atomics in flight per thread.
__global__ void k_count_deg(const int* __restrict__ dst, int* __restrict__ deg, int E) {
  const int T = gridDim.x * blockDim.x;
  const int e0 = blockIdx.x * blockDim.x + threadIdx.x;
#pragma unroll
  for (int j = 0; j < 8; ++j) {
    const int e = e0 + j * T;
    if (e < E) atomicAdd(deg + dst[e], 1);
  }
}

// pass 1: per-1024-block inclusive scan -> loc; block total -> part[bid]
__global__ __launch_bounds__(1024)
void k_scan1(const int* __restrict__ deg, int* __restrict__ loc, int* __restrict__ part, int n) {
  __shared__ int wsum[16];
  const int tid = threadIdx.x;
  const int lane = tid & 63, wid = tid >> 6;
  const int i = blockIdx.x * 1024 + tid;
  const int v = (i < n) ? deg[i] : 0;
  int incl = v;
#pragma unroll
  for (int off = 1; off < 64; off <<= 1) {
    int t = __shfl_up(incl, off);
    if (lane >= off) incl += t;
  }
  if (lane == 63) wsum[wid] = incl;
  __syncthreads();
  if (wid == 0) {
    int wv = (lane < 16) ? wsum[lane] : 0;
#pragma unroll
    for (int off = 1; off < 16; off <<= 1) {
      int t = __shfl_up(wv, off);
      if (lane >= off) wv += t;
    }
    if (lane < 16) wsum[lane] = wv;
  }
  __syncthreads();
  const int woff = (wid > 0) ? wsum[wid - 1] : 0;
  if (i < n) loc[i] = woff + incl;      // inclusive within block
  if (tid == 1023) part[blockIdx.x] = woff + incl;
}

// pass 2: single block scans nb (<=1024) partials -> exclusive; part[nb]=total
__global__ __launch_bounds__(1024)
void k_scan2(int* __restrict__ part, int nb) {
  __shared__ int wsum[16];
  const int tid = threadIdx.x;
  const int lane = tid & 63, wid = tid >> 6;
  const int v = (tid < nb) ? part[tid] : 0;
  int incl = v;
#pragma unroll
  for (int off = 1; off < 64; off <<= 1) {
    int t = __shfl_up(incl, off);
    if (lane >= off) incl += t;
  }
  if (lane == 63) wsum[wid] = incl;
  __syncthreads();
  if (wid == 0) {
    int wv = (lane < 16) ? wsum[lane] : 0;
#pragma unroll
    for (int off = 1; off < 16; off <<= 1) {
      int t = __shfl_up(wv, off);
      if (lane >= off) wv += t;
    }
    if (lane < 16) wsum[lane] = wv;
  }
  __syncthreads();
  const int woff = (wid > 0) ? wsum[wid - 1] : 0;
  if (tid < nb) part[tid] = woff + incl - v;  // exclusive
  if (tid == 0) part[nb] = wsum[15];          // total
}

// pass 3: apply offsets; emit row_off / cursor / deg_inv
__global__ __launch_bounds__(256)
void k_scan3(const int* __restrict__ deg, const int* __restrict__ loc, const int* __restrict__ part,
             int* __restrict__ row_off, int* __restrict__ cursor, float* __restrict__ deg_inv,
             int n, int nb) {
  const int i = blockIdx.x * blockDim.x + threadIdx.x;
  if (i < n) {
    const int v = deg[i];
    const int ro = part[i >> 10] + loc[i] - v;
    row_off[i] = ro;
    cursor[i] = ro;
    deg_inv[i] = 1.0f / (float)((v > 1) ? v : 1);
  }
  if (i == 0) row_off[n] = part[nb];
}

// x8 edges per thread: gather inputs, 8 independent atomic-returns, 8 stores.
__global__ void k_fill_csr(const int* __restrict__ src, const int* __restrict__ dst,
                           int* __restrict__ cursor, int* __restrict__ esrc, int E) {
  const int T = gridDim.x * blockDim.x;
  const int e0 = blockIdx.x * blockDim.x + threadIdx.x;
  int dv[8], sv[8], pv[8];
#pragma unroll
  for (int j = 0; j < 8; ++j) {
    const int e = e0 + j * T;
    if (e < E) { dv[j] = dst[e]; sv[j] = src[e]; }
  }
#pragma unroll
  for (int j = 0; j < 8; ++j) {
    const int e = e0 + j * T;
    if (e < E) pv[j] = atomicAdd(cursor + dv[j], 1);
  }
#pragma unroll
  for (int j = 0; j < 8; ++j) {
    const int e = e0 + j * T;
    if (e < E) esrc[pv[j]] = sv[j];
  }
}

// ---------------- x: f32 -> bf16 plain conversion --------------------------
__global__ __launch_bounds__(256)
void k_conv_x(const float* __restrict__ src, unsigned short* __restrict__ dst, int n4) {
  for (int i = blockIdx.x * blockDim.x + threadIdx.x; i < n4; i += gridDim.x * blockDim.x) {
    const float4 v = *((const float4*)src + i);
    uint2 o;
    o.x = packbf(v.x, v.y);
    o.y = packbf(v.z, v.w);
    *((uint2*)dst + i) = o;
  }
}

// ---------------- weights: f32 -> bf16 packed chunk-major ------------------
// dst idx (bf16 units) = kt64*(Opack*64) + chunk*(Opack*8) + (col+colOff)*8 + j
// holds src[col][kt64*64 + chunk*8 + j], chunk in 0..7.
struct PackJob { const float* src; unsigned short* dst; int O; int K; int colOff; int Opack; };
struct PackJobs { PackJob j[10]; };

__global__ __launch_bounds__(256)
void k_pack_w(PackJobs jobs) {
  const PackJob J = jobs.j[blockIdx.y];
  const int total = J.O * J.K / 2;  // u32 outputs, source-major
  for (int u = blockIdx.x * blockDim.x + threadIdx.x; u < total; u += gridDim.x * blockDim.x) {
    const int e = u * 2;
    const int col = e / J.K;
    const int k = e - col * J.K;
    const int kt = k >> 6, ch = (k >> 3) & 7, j = k & 7;
    const float f0 = J.src[(size_t)col * J.K + k];
    const float f1 = J.src[(size_t)col * J.K + k + 1];
    const int didx = kt * (J.Opack * 64) + ch * (J.Opack * 8) + (col + J.colOff) * 8 + j;
    ((unsigned int*)J.dst)[didx >> 1] = packbf(f0, f1);
  }
}

// ---------------- mean aggregation, bf16 in/out, f32 accum -----------------
static __device__ __forceinline__ void acc_u4(float* acc, const uint4& v) {
  acc[0] += lo16(v.x); acc[1] += hi16(v.x);
  acc[2] += lo16(v.y); acc[3] += hi16(v.y);
  acc[4] += lo16(v.z); acc[5] += hi16(v.z);
  acc[6] += lo16(v.w); acc[7] += hi16(v.w);
}

// K=128: row = 16 uint4; 4 subgroups of 16 lanes; 32-edge batches.
__global__ __launch_bounds__(256)
void k_agg128(const unsigned short* __restrict__ h, const int* __restrict__ row_off,
              const int* __restrict__ esrc, const float* __restrict__ deg_inv,
              unsigned short* __restrict__ agg, int N) {
  const int node = blockIdx.x * 4 + (threadIdx.x >> 6);
  if (node >= N) return;
  const int lane = threadIdx.x & 63;
  const int g = lane >> 4, c = lane & 15;
  const int s0 = row_off[node], s1 = row_off[node + 1];
  const uint4* hp = (const uint4*)h;
  float acc[8] = {0.f, 0.f, 0.f, 0.f, 0.f, 0.f, 0.f, 0.f};
  for (int i = s0; i < s1; i += 32) {
    int el = i + (lane & 31);
    if (el >= s1) el = s1 - 1;
    const int ev = esrc[el];
    uint4 v[8];
#pragma unroll
    for (int u = 0; u < 8; ++u) {
      if (i + u * 4 < s1) {                        // wave-uniform
        const int e = __shfl(ev, u * 4 + g);
        v[u] = hp[(size_t)e * 16 + c];
      }
    }
#pragma unroll
    for (int u = 0; u < 8; ++u)
      if (i + u * 4 + g < s1) acc_u4(acc, v[u]);
  }
#pragma unroll
  for (int j = 0; j < 8; ++j) {
    acc[j] += __shfl_xor(acc[j], 16);
    acc[j] += __shfl_xor(acc[j], 32);
  }
  if (g == 0) {
    const float di = deg_inv[node];
    uint4 o;
    o.x = packbf(acc[0] * di, acc[1] * di);
    o.y = packbf(acc[2] * di, acc[3] * di);
    o.z = packbf(acc[4] * di, acc[5] * di);
    o.w = packbf(acc[6] * di, acc[7] * di);
    ((uint4*)agg)[(size_t)node * 16 + c] = o;
  }
}

// K=256: row = 32 uint4; 2 subgroups of 32 lanes; 32-edge batches.
__global__ __launch_bounds__(256)
void k_agg256(const unsigned short* __restrict__ h, const int* __restrict__ row_off,
              const int* __restrict__ esrc, const float* __restrict__ deg_inv,
              unsigned short* __restrict__ agg, int N) {
  const int node = blockIdx.x * 4 + (threadIdx.x >> 6);
  if (node >= N) return;
  const int lane = threadIdx.x & 63;
  const int g = lane >> 5, c = lane & 31;
  const int s0 = row_off[node], s1 = row_off[node + 1];
  const uint4* hp = (const uint4*)h;
  float acc[8] = {0.f, 0.f, 0.f, 0.f, 0.f, 0.f, 0.f, 0.f};
  for (int i = s0; i < s1; i += 32) {
    int el = i + (lane & 31);
    if (el >= s1) el = s1 - 1;
    const int ev = esrc[el];
    uint4 v[16];
#pragma unroll
    for (int u = 0; u < 16; ++u) {
      if (i + u * 2 < s1) {                        // wave-uniform
        const int e = __shfl(ev, u * 2 + g);
        v[u] = hp[(size_t)e * 32 + c];
      }
    }
#pragma unroll
    for (int u = 0; u < 16; ++u)
      if (i + u * 2 + g < s1) acc_u4(acc, v[u]);
  }
#pragma unroll
  for (int j = 0; j < 8; ++j) acc[j] += __shfl_xor(acc[j], 32);
  if (g == 0) {
    const float di = deg_inv[node];
    uint4 o;
    o.x = packbf(acc[0] * di, acc[1] * di);
    o.y = packbf(acc[2] * di, acc[3] * di);
    o.z = packbf(acc[4] * di, acc[5] * di);
    o.w = packbf(acc[6] * di, acc[7] * di);
    ((uint4*)agg)[(size_t)node * 32 + c] = o;
  }
}

// K=64: row = 8 uint4; 8 subgroups of 8 lanes; 32-edge batches.
__global__ __launch_bounds__(256)
void k_agg64(const unsigned short* __restrict__ h, const int* __restrict__ row_off,
             const int* __restrict__ esrc, const float* __restrict__ deg_inv,
             unsigned short* __restrict__ agg, int N) {
  const int node = blockIdx.x * 4 + (threadIdx.x >> 6);
  if (node >= N) return;
  const int lane = threadIdx.x & 63;
  const int g = lane >> 3, c = lane & 7;
  const int s0 = row_off[node], s1 = row_off[node + 1];
  const uint4* hp = (const uint4*)h;
  float acc[8] = {0.f, 0.f, 0.f, 0.f, 0.f, 0.f, 0.f, 0.f};
  for (int i = s0; i < s1; i += 32) {
    int el = i + (lane & 31);
    if (el >= s1) el = s1 - 1;
    const int ev = esrc[el];
    uint4 v[4];
#pragma unroll
    for (int u = 0; u < 4; ++u) {
      if (i + u * 8 < s1) {                        // wave-uniform
        const int e = __shfl(ev, u * 8 + g);
        v[u] = hp[(size_t)e * 8 + c];
      }
    }
#pragma unroll
    for (int u = 0; u < 4; ++u)
      if (i + u * 8 + g < s1) acc_u4(acc, v[u]);
  }
#pragma unroll
  for (int j = 0; j < 8; ++j) {
    acc[j] += __shfl_xor(acc[j], 8);
    acc[j] += __shfl_xor(acc[j], 16);
    acc[j] += __shfl_xor(acc[j], 32);
  }
  if (g == 0) {
    const float di = deg_inv[node];
    uint4 o;
    o.x = packbf(acc[0] * di, acc[1] * di);
    o.y = packbf(acc[2] * di, acc[3] * di);
    o.z = packbf(acc[4] * di, acc[5] * di);
    o.w = packbf(acc[6] * di, acc[7] * di);
    ((uint4*)agg)[(size_t)node * 8 + c] = o;
  }
}

// L1 fused post-transform aggregate: z = [Zl | Yr] (N x 128 bf16).
// out[n][0..63] = relu(deg_inv[n] * sum_e Zl[src(e)] + Yr[n] + bias).
__global__ __launch_bounds__(256)
void k_agg_post64(const unsigned short* __restrict__ z, const int* __restrict__ row_off,
                  const int* __restrict__ esrc, const float* __restrict__ deg_inv,
                  const float* __restrict__ bias, unsigned short* __restrict__ out, int N) {
  const int node = blockIdx.x * 4 + (threadIdx.x >> 6);
  if (node >= N) return;
  const int lane = threadIdx.x & 63;
  const int g = lane >> 3, c = lane & 7;
  const int s0 = row_off[node], s1 = row_off[node + 1];
  const uint4* zp = (const uint4*)z;   // row = 16 uint4; Zl = first 8
  float acc[8] = {0.f, 0.f, 0.f, 0.f, 0.f, 0.f, 0.f, 0.f};
  for (int i = s0; i < s1; i += 32) {
    int el = i + (lane & 31);
    if (el >= s1) el = s1 - 1;
    const int ev = esrc[el];
    uint4 v[4];
#pragma unroll
    for (int u = 0; u < 4; ++u) {
      if (i + u * 8 < s1) {
        const int e = __shfl(ev, u * 8 + g);
        v[u] = zp[(size_t)e * 16 + c];
      }
    }
#pragma unroll
    for (int u = 0; u < 4; ++u)
      if (i + u * 8 + g < s1) acc_u4(acc, v[u]);
  }
#pragma unroll
  for (int j = 0; j < 8; ++j) {
    acc[j] += __shfl_xor(acc[j], 8);
    acc[j] += __shfl_xor(acc[j], 16);
    acc[j] += __shfl_xor(acc[j], 32);
  }
  if (g == 0) {
    const float di = deg_inv[node];
    const uint4 yr = zp[(size_t)node * 16 + 8 + c];
    float y[8];
    y[0] = lo16(yr.x); y[1] = hi16(yr.x); y[2] = lo16(yr.y); y[3] = hi16(yr.y);
    y[4] = lo16(yr.z); y[5] = hi16(yr.z); y[6] = lo16(yr.w); y[7] = hi16(yr.w);
    float r[8];
#pragma unroll
    for (int j = 0; j < 8; ++j)
      r[j] = fmaxf(acc[j] * di + y[j] + bias[c * 8 + j], 0.f);
    uint4 o;
    o.x = packbf(r[0], r[1]);
    o.y = packbf(r[2], r[3]);
    o.z = packbf(r[4], r[5]);
    o.w = packbf(r[6], r[7]);
    ((uint4*)out)[(size_t)node * 8 + c] = o;
  }
}

// ---------------- fused SAGE GEMM ------------------------------------------
// FUSED=true : C = relu(A0@B0p^T + A1@B1p^T + bias)  (two phases)
// FUSED=false: C = A0@B0p^T                           (single phase, raw)
// HEAD=true  : don't store C; LDS-transpose + per-row 4-class partial dot
//              with W4 slice -> Pb[cb][row][4] (head fused into epilogue).
// Block: 128 rows x BN=WC*64 cols; 2 x WC waves; MFMA 32x32x16; BK=64.
// A staged in LDS (32KB dbuf); B direct from global packed layout, hoisted.
// 1D grid, XCD-co-located decode: r8=bid&7, cb=(bid>>3)%NCB, rowp=((bid>>3)/NCB)*8+r8
template <int WC, int NCB, bool FUSED, bool HEAD>
__global__ __launch_bounds__(WC * 128)
void k_sage_gemm(const unsigned short* __restrict__ A0, const unsigned short* __restrict__ B0,
                 const unsigned short* __restrict__ A1, const unsigned short* __restrict__ B1,
                 const float* __restrict__ bias, unsigned short* __restrict__ C,
                 const float* __restrict__ W4g, float* __restrict__ Pb,
                 int Nn, int K, int O) {
  constexpr int BN = WC * 64;
  constexpr int T = WC * 128;
  constexpr int ACH = 1024;            // A 16B-chunks per tile (128 rows x 8)
  constexpr int LPT = ACH / T;         // A chunks per thread per stage
  constexpr int LDS_SZ = HEAD ? (2 * 16384 + 2048) : (2 * 16384);
  __shared__ char lds[LDS_SZ];

  const int nrp = (Nn + 127) >> 7;
  const int bid = blockIdx.x;
  const int r8 = bid & 7;
  const int tb = bid >> 3;
  const int cb = tb % NCB;
  const int rowp = (tb / NCB) * 8 + r8;
  if (rowp >= nrp) return;

  const int tid = threadIdx.x;
  const int w = tid >> 6, lane = tid & 63;
  const int wr = w / WC, wc = w % WC;
  const int fr = lane & 31, fq = lane >> 5;
  const int row0 = rowp * 128 + wr * 64;
  const int colb = cb * BN;

  if constexpr (HEAD) {
    // stage W4 column slice [4][BN] into LDS tail (barriers in main loop cover)
    float* w4s = (float*)(lds + 32768);
#pragma unroll
    for (int ii = 0; ii < 2 * BN * 4 / T / 2; ++ii) {  // = 2 for WC=2
      const int idx = tid * 2 + ii;  // interleaved is fine; cover 0..4*BN-1
    }
    const int i0 = tid * 2;
#pragma unroll
    for (int ii = 0; ii < 2; ++ii) {
      const int idx = i0 + ii;               // 0..511 (WC=2 -> 4*128)
      if (idx < 4 * BN)
        w4s[idx] = W4g[(idx >> 7) * 512 + colb + (idx & (BN - 1))];
    }
  }

  const int KT0 = K >> 6;        // 64-wide tiles per phase
  const int NT = FUSED ? 2 * KT0 : KT0;

  f32x16 acc[2][2];
#pragma unroll
  for (int m = 0; m < 2; ++m)
#pragma unroll
    for (int cn = 0; cn < 2; ++cn)
#pragma unroll
      for (int r = 0; r < 16; ++r) acc[m][cn][r] = 0.f;

  auto stage = [&](int buf, int t) {
    const unsigned short* Ab;
    int ktl;
    if (FUSED) {
      const int ph = (t >= KT0) ? 1 : 0;
      Ab = ph ? A1 : A0;
      ktl = t - ph * KT0;
    } else {
      Ab = A0; ktl = t;
    }
    char* lb = lds + buf * 16384;
#pragma unroll
    for (int i = 0; i < LPT; ++i) {
      const int ch = tid + i * T;
      const int ar = ch >> 3, s = ch & 7;           // LDS row, slot
      int g = rowp * 128 + ar;
      if (g >= Nn) g = Nn - 1;
      // inverse-swizzled global source; linear LDS dest
      gl_lds16(Ab + (size_t)g * K + ktl * 64 + ((s ^ (ar & 7)) << 3), lb + ch * 16);
    }
  };

  stage(0, 0);
#pragma unroll 1
  for (int t = 0; t < NT; ++t) {
    asm volatile("s_waitcnt vmcnt(0)" ::: "memory");
    __syncthreads();
    // B pointer for this tile (global, packed chunk-major)
    const unsigned short* Bp;
    int ktl;
    if (FUSED) {
      const int ph = (t >= KT0) ? 1 : 0;
      Bp = ph ? B1 : B0;
      ktl = t - ph * KT0;
    } else {
      Bp = B0; ktl = t;
    }
    const unsigned short* Bbase = Bp + (size_t)ktl * (O * 64) + (size_t)(colb + wc * 64) * 8;
    // HOIST: issue all 8 B loads for this tile up front (oldest in queue)
    bf16x8 bg[4][2];
#pragma unroll
    for (int k16i = 0; k16i < 4; ++k16i) {
      const int c = k16i * 2 + fq;                  // chunk 0..7
#pragma unroll
      for (int cn = 0; cn < 2; ++cn)
        bg[k16i][cn] = *(const bf16x8*)(Bbase + (size_t)c * (O * 8) + (cn * 32 + fr) * 8);
    }
    if (t + 1 < NT) stage((t + 1) & 1, t + 1);
    const char* lb = lds + (t & 1) * 16384;
#pragma unroll
    for (int k16i = 0; k16i < 4; ++k16i) {
      const int c = k16i * 2 + fq;                  // chunk 0..7
      bf16x8 af[2];
#pragma unroll
      for (int m = 0; m < 2; ++m) {
        const int rl = wr * 64 + m * 32 + fr;
        af[m] = *(const bf16x8*)(lb + rl * 128 + ((c ^ (rl & 7)) << 4));
      }
#pragma unroll
      for (int m = 0; m < 2; ++m)
#pragma unroll
        for (int cn = 0; cn < 2; ++cn)
          acc[m][cn] = __builtin_amdgcn_mfma_f32_32x32x16_bf16(af[m], bg[k16i][cn], acc[m][cn], 0, 0, 0);
    }
  }

  if constexpr (HEAD) {
    // ---- fused head epilogue (WC==2: 128x128 chunk) ----
    __syncthreads();                    // all waves done with LDS A-buffers
    unsigned int* lh = (unsigned int*)lds;        // [128][64] u32, row-rotated
    float* w4s = (float*)(lds + 32768);
#pragma unroll
    for (int cn = 0; cn < 2; ++cn) {
      const int coll = wc * 64 + cn * 32 + fr;    // block-local col
      const float bb = bias[colb + coll];
#pragma unroll
      for (int m = 0; m < 2; ++m) {
#pragma unroll
        for (int reg = 0; reg < 16; ++reg) {
          const float v = fmaxf(acc[m][cn][reg] + bb, 0.f);
          const float nb = __shfl_xor(v, 1);
          const int rowl = wr * 64 + m * 32 + (reg & 3) + 8 * (reg >> 2) + 4 * fq;
          if (!(lane & 1)) {
            const int c2 = coll >> 1;
            lh[rowl * 64 + ((c2 + rowl) & 63)] = packbf(v, nb);
          }
        }
      }
    }
    __syncthreads();
    if (tid < 128) {
      const int rowl = tid;
      float p0 = 0.f, p1 = 0.f, p2 = 0.f, p3 = 0.f;
#pragma unroll
      for (int j = 0; j < 64; ++j) {
        const unsigned int u = lh[rowl * 64 + ((j + rowl) & 63)];
        const float lo = lo16(u), hi = hi16(u);
        const int cl = 2 * j, ch = 2 * j + 1;
        p0 += lo * w4s[cl] + hi * w4s[ch];
        p1 += lo * w4s[128 + cl] + hi * w4s[128 + ch];
        p2 += lo * w4s[256 + cl] + hi * w4s[256 + ch];
        p3 += lo * w4s[384 + cl] + hi * w4s[384 + ch];
      }
      const int rg = rowp * 128 + rowl;
      if (rg < Nn) {
        float4 o; o.x = p0; o.y = p1; o.z = p2; o.w = p3;
        *(float4*)(Pb + ((size_t)cb * Nn + rg) * 4) = o;
      }
    }
    return;
  }

  // epilogue. C/D map: col = lane&31, row = (reg&3) + 8*(reg>>2) + 4*(lane>>5).
#pragma unroll
  for (int cn = 0; cn < 2; ++cn) {
    const int col = colb + wc * 64 + cn * 32 + fr;
    float bb = 0.f;
    if (FUSED) bb = bias[col];
#pragma unroll
    for (int m = 0; m < 2; ++m) {
#pragma unroll
      for (int reg = 0; reg < 16; ++reg) {
        float v = acc[m][cn][reg];
        if (FUSED) v = fmaxf(v + bb, 0.f);
        const float nb = __shfl_xor(v, 1);
        const int row = row0 + m * 32 + (reg & 3) + 8 * (reg >> 2) + 4 * fq;
        if (!(lane & 1) && row < Nn) {
          *(unsigned int*)(C + (size_t)row * O + col) = packbf(v, nb);
        }
      }
    }
  }
}

// ---------------- head final: sum NCB=4 partials + bias + softmax ----------
__global__ __launch_bounds__(256)
void k_head_final(const float* __restrict__ Pb, const float* __restrict__ b,
                  float* __restrict__ out, int N) {
  const int n = blockIdx.x * blockDim.x + threadIdx.x;
  if (n >= N) return;
  const float4 q0 = *(const float4*)(Pb + (size_t)n * 4);
  const float4 q1 = *(const float4*)(Pb + ((size_t)N + n) * 4);
  const float4 q2 = *(const float4*)(Pb + ((size_t)2 * N + n) * 4);
  const float4 q3 = *(const float4*)(Pb + ((size_t)3 * N + n) * 4);
  const float l0 = q0.x + q1.x + q2.x + q3.x + b[0];
  const float l1 = q0.y + q1.y + q2.y + q3.y + b[1];
  const float l2 = q0.z + q1.z + q2.z + q3.z + b[2];
  const float l3 = q0.w + q1.w + q2.w + q3.w + b[3];
  const float m = fmaxf(fmaxf(l0, l1), fmaxf(l2, l3));
  const float e0 = expf(l0 - m), e1 = expf(l1 - m), e2 = expf(l2 - m), e3 = expf(l3 - m);
  const float inv = 1.0f / (e0 + e1 + e2 + e3);
  float4 r; r.x = e0 * inv; r.y = e1 * inv; r.z = e2 * inv; r.w = e3 * inv;
  *(float4*)(out + (size_t)n * 4) = r;
}

// ---------------------------------------------------------------------------
extern "C" void kernel_launch(void* const* d_in, const int* in_sizes, int n_in,
                              void* d_out, int out_size, void* d_ws, size_t ws_size,
                              hipStream_t stream) {
  const float* x = (const float*)d_in[0];
  const float* Wl[5] = {(const float*)d_in[1], (const float*)d_in[4], (const float*)d_in[7],
                        (const float*)d_in[10], (const float*)d_in[13]};
  const float* bl[5] = {(const float*)d_in[2], (const float*)d_in[5], (const float*)d_in[8],
                        (const float*)d_in[11], (const float*)d_in[14]};
  const float* Wr[5] = {(const float*)d_in[3], (const float*)d_in[6], (const float*)d_in[9],
                        (const float*)d_in[12], (const float*)d_in[15]};
  const float* Wout = (const float*)d_in[16];
  const float* bout = (const float*)d_in[17];
  const int* eidx = (const int*)d_in[18];

  const int N = in_sizes[0] / 128;
  const int E = in_sizes[18] / 2;
  const int* srcI = eidx;
  const int* dstI = eidx + E;

  const int Kd[5] = {128, 128, 64, 128, 256};
  const int Od[5] = {128, 64, 128, 256, 512};

  // workspace carve-out (256B aligned)
  char* ws = (char*)d_ws;
  size_t p = 0;
  auto alloc = [&](size_t bytes) { size_t r = p; p += (bytes + 255) & ~(size_t)255; return r; };
  int*   deg     = (int*)(ws + alloc((size_t)N * 4));
  int*   row_off = (int*)(ws + alloc((size_t)(N + 1) * 4));
  int*   cursor  = (int*)(ws + alloc((size_t)N * 4));
  float* deg_inv = (float*)(ws + alloc((size_t)N * 4));
  int*   loc     = (int*)(ws + alloc((size_t)N * 4));
  int*   part    = (int*)(ws + alloc((size_t)1032 * 4));
  int*   esrc    = (int*)(ws + alloc((size_t)E * 4));
  unsigned short* xb = (unsigned short*)(ws + alloc((size_t)N * 128 * 2));
  unsigned short* wlb[5];
  unsigned short* wrb[5];
  for (int l = 0; l < 5; ++l) {
    wlb[l] = (unsigned short*)(ws + alloc((size_t)Od[l] * Kd[l] * 2));
    wrb[l] = (unsigned short*)(ws + alloc((size_t)Od[l] * Kd[l] * 2));
  }
  unsigned short* wcat1 = (unsigned short*)(ws + alloc((size_t)128 * 128 * 2));
  unsigned short* bufA = (unsigned short*)(ws + alloc((size_t)N * 512 * 2));
  unsigned short* bufB = (unsigned short*)(ws + alloc((size_t)N * 256 * 2));
  unsigned short* agg  = (unsigned short*)(ws + alloc((size_t)N * 256 * 2));
  float* Pb = (float*)(ws + alloc((size_t)4 * N * 4 * 4));
  (void)ws_size; (void)n_in; (void)out_size;

  // ---- conversions: x plain; weights packed chunk-major ----
  k_conv_x<<<128, 256, 0, stream>>>(x, xb, N * 128 / 4);
  PackJobs jobs;
  for (int l = 0; l < 5; ++l) {
    if (l == 1) {
      jobs.j[2] = {Wl[1], wcat1, 64, 128, 0, 128};   // Zl cols 0..63
      jobs.j[3] = {Wr[1], wcat1, 64, 128, 64, 128};  // Yr cols 64..127
    } else {
      jobs.j[2 * l]     = {Wl[l], wlb[l], Od[l], Kd[l], 0, Od[l]};
      jobs.j[2 * l + 1] = {Wr[l], wrb[l], Od[l], Kd[l], 0, Od[l]};
    }
  }
  k_pack_w<<<dim3(32, 10), 256, 0, stream>>>(jobs);

  // ---- CSR build (multi-block scan; x8-batched atomics) ----
  hipMemsetAsync(deg, 0, (size_t)N * 4, stream);
  k_count_deg<<<idiv_up(E, 2048), 256, 0, stream>>>(dstI, deg, E);
  const int nb = idiv_up(N, 1024);
  k_scan1<<<nb, 1024, 0, stream>>>(deg, loc, part, N);
  k_scan2<<<1, 1024, 0, stream>>>(part, nb);
  k_scan3<<<idiv_up(N + 1, 256), 256, 0, stream>>>(deg, loc, part, row_off, cursor, deg_inv, N, nb);
  k_fill_csr<<<idiv_up(E, 2048), 256, 0, stream>>>(srcI, dstI, cursor, esrc, E);

  const int gx8 = 8 * ((idiv_up(N, 128) + 7) / 8);   // padded row-panel grid

  // ---- layer 0: K=128, O=128 ----
  k_agg128<<<idiv_up(N, 4), 256, 0, stream>>>(xb, row_off, esrc, deg_inv, agg, N);
  k_sage_gemm<2, 1, true, false><<<gx8, 256, 0, stream>>>(
      agg, wlb[0], xb, wrb[0], bl[0], bufA, nullptr, nullptr, N, 128, 128);

  // ---- layer 1 (linearity swap): Z|Yr = h1 @ [Wl;Wr]^T, then fused agg ----
  k_sage_gemm<2, 1, false, false><<<gx8, 256, 0, stream>>>(
      bufA, wcat1, bufA, wcat1, bl[1], agg, nullptr, nullptr, N, 128, 128);
  k_agg_post64<<<idiv_up(N, 4), 256, 0, stream>>>(agg, row_off, esrc, deg_inv, bl[1], bufB, N);

  // ---- layer 2: K=64, O=128 ----
  k_agg64<<<idiv_up(N, 4), 256, 0, stream>>>(bufB, row_off, esrc, deg_inv, agg, N);
  k_sage_gemm<2, 1, true, false><<<gx8, 256, 0, stream>>>(
      agg, wlb[2], bufB, wrb[2], bl[2], bufA, nullptr, nullptr, N, 64, 128);

  // ---- layer 3: K=128, O=256 (2 col-blocks, XCD-co-located) ----
  k_agg128<<<idiv_up(N, 4), 256, 0, stream>>>(bufA, row_off, esrc, deg_inv, agg, N);
  k_sage_gemm<2, 2, true, false><<<2 * gx8, 256, 0, stream>>>(
      agg, wlb[3], bufA, wrb[3], bl[3], bufB, nullptr, nullptr, N, 128, 256);

  // ---- layer 4: K=256, O=512 (4 col-blocks); head fused into epilogue ----
  k_agg256<<<idiv_up(N, 4), 256, 0, stream>>>(bufB, row_off, esrc, deg_inv, agg, N);
  k_sage_gemm<2, 4, true, true><<<4 * gx8, 256, 0, stream>>>(
      agg, wlb[4], bufB, wrb[4], bl[4], nullptr, Wout, Pb, N, 256, 512);

  k_head_final<<<idiv_up(N, 256), 256, 0, stream>>>(Pb, bout, (float*)d_out, N);
}

// Round 16
// 393.518 us; speedup vs baseline: 1.1424x; 1.1424x over previous
//
#include <hip/hip_runtime.h>
#include <hip/hip_bf16.h>
#include <cstdint>
#include <cstddef>

// ---------------------------------------------------------------------------
// SAGE GNN forward, bf16 MFMA 32x32x16, LDS-staged GEMM, BK=64.
//  - GEMM: round-6 schedule + XCD-co-located col-blocks; B direct from global
//    (packed, L2-resident), per-tile B loads hoisted. VGPR budget 76 -- do not
//    add epilogue complexity (rounds 8/15 lesson: occupancy cliff).
//  - L1: linearity swap (raw GEMM then 64-wide fused aggregate)
//  - aggregates: uint4 lanes, 32-edge shfl-broadcast batches
//  - CSR: x8-batched atomics; head: W4 staged in LDS
// ---------------------------------------------------------------------------

typedef short bf16x8 __attribute__((ext_vector_type(8)));   // 8 bf16 = 4 VGPRs
typedef float f32x16 __attribute__((ext_vector_type(16)));

static inline int idiv_up(int a, int b) { return (a + b - 1) / b; }

static __device__ __forceinline__ float bf2f(unsigned short u) {
  union { unsigned int i; float f; } v; v.i = ((unsigned int)u) << 16; return v.f;
}
static __device__ __forceinline__ unsigned short f2bf(float f) {
  union { float f; unsigned int i; } v; v.f = f;
  return (unsigned short)((v.i + 0x7FFFu + ((v.i >> 16) & 1u)) >> 16);  // RNE
}
static __device__ __forceinline__ float lo16(unsigned int u) { return bf2f((unsigned short)(u & 0xffffu)); }
static __device__ __forceinline__ float hi16(unsigned int u) { return bf2f((unsigned short)(u >> 16)); }
static __device__ __forceinline__ unsigned int packbf(float a, float b) {
  return (unsigned int)f2bf(a) | ((unsigned int)f2bf(b) << 16);
}

// async global->LDS, 16B per lane. LDS dest: wave-uniform base + lane*16.
static __device__ __forceinline__ void gl_lds16(const void* g, void* l) {
  typedef __attribute__((address_space(3))) unsigned int lds_u32;
  typedef __attribute__((address_space(1))) const unsigned int glb_u32;
  __builtin_amdgcn_global_load_lds((glb_u32*)(uintptr_t)g,
                                   (lds_u32*)(unsigned int)(uintptr_t)l, 16, 0, 0);
}

// ---------------- CSR build ----------------
// x8 edges per thread (strided): 8 independent atomics in flight per thread.
__global__ void k_count_deg(const int* __restrict__ dst, int* __restrict__ deg, int E) {
  const int T = gridDim.x * blockDim.x;
  const int e0 = blockIdx.x * blockDim.x + threadIdx.x;
#pragma unroll
  for (int j = 0; j < 8; ++j) {
    const int e = e0 + j * T;
    if (e < E) atomicAdd(deg + dst[e], 1);
  }
}

// pass 1: per-1024-block inclusive scan -> loc; block total -> part[bid]
__global__ __launch_bounds__(1024)
void k_scan1(const int* __restrict__ deg, int* __restrict__ loc, int* __restrict__ part, int n) {
  __shared__ int wsum[16];
  const int tid = threadIdx.x;
  const int lane = tid & 63, wid = tid >> 6;
  const int i = blockIdx.x * 1024 + tid;
  const int v = (i < n) ? deg[i] : 0;
  int incl = v;
#pragma unroll
  for (int off = 1; off < 64; off <<= 1) {
    int t = __shfl_up(incl, off);
    if (lane >= off) incl += t;
  }
  if (lane == 63) wsum[wid] = incl;
  __syncthreads();
  if (wid == 0) {
    int wv = (lane < 16) ? wsum[lane] : 0;
#pragma unroll
    for (int off = 1; off < 16; off <<= 1) {
      int t = __shfl_up(wv, off);
      if (lane >= off) wv += t;
    }
    if (lane < 16) wsum[lane] = wv;
  }
  __syncthreads();
  const int woff = (wid > 0) ? wsum[wid - 1] : 0;
  if (i < n) loc[i] = woff + incl;      // inclusive within block
  if (tid == 1023) part[blockIdx.x] = woff + incl;
}

// pass 2: single block scans nb (<=1024) partials -> exclusive; part[nb]=total
__global__ __launch_bounds__(1024)
void k_scan2(int* __restrict__ part, int nb) {
  __shared__ int wsum[16];
  const int tid = threadIdx.x;
  const int lane = tid & 63, wid = tid >> 6;
  const int v = (tid < nb) ? part[tid] : 0;
  int incl = v;
#pragma unroll
  for (int off = 1; off < 64; off <<= 1) {
    int t = __shfl_up(incl, off);
    if (lane >= off) incl += t;
  }
  if (lane == 63) wsum[wid] = incl;
  __syncthreads();
  if (wid == 0) {
    int wv = (lane < 16) ? wsum[lane] : 0;
#pragma unroll
    for (int off = 1; off < 16; off <<= 1) {
      int t = __shfl_up(wv, off);
      if (lane >= off) wv += t;
    }
    if (lane < 16) wsum[lane] = wv;
  }
  __syncthreads();
  const int woff = (wid > 0) ? wsum[wid - 1] : 0;
  if (tid < nb) part[tid] = woff + incl - v;  // exclusive
  if (tid == 0) part[nb] = wsum[15];          // total
}

// pass 3: apply offsets; emit row_off / cursor / deg_inv
__global__ __launch_bounds__(256)
void k_scan3(const int* __restrict__ deg, const int* __restrict__ loc, const int* __restrict__ part,
             int* __restrict__ row_off, int* __restrict__ cursor, float* __restrict__ deg_inv,
             int n, int nb) {
  const int i = blockIdx.x * blockDim.x + threadIdx.x;
  if (i < n) {
    const int v = deg[i];
    const int ro = part[i >> 10] + loc[i] - v;
    row_off[i] = ro;
    cursor[i] = ro;
    deg_inv[i] = 1.0f / (float)((v > 1) ? v : 1);
  }
  if (i == 0) row_off[n] = part[nb];
}

// x8 edges per thread: gather inputs, 8 independent atomic-returns, 8 stores.
__global__ void k_fill_csr(const int* __restrict__ src, const int* __restrict__ dst,
                           int* __restrict__ cursor, int* __restrict__ esrc, int E) {
  const int T = gridDim.x * blockDim.x;
  const int e0 = blockIdx.x * blockDim.x + threadIdx.x;
  int dv[8], sv[8], pv[8];
#pragma unroll
  for (int j = 0; j < 8; ++j) {
    const int e = e0 + j * T;
    if (e < E) { dv[j] = dst[e]; sv[j] = src[e]; }
  }
#pragma unroll
  for (int j = 0; j < 8; ++j) {
    const int e = e0 + j * T;
    if (e < E) pv[j] = atomicAdd(cursor + dv[j], 1);
  }
#pragma unroll
  for (int j = 0; j < 8; ++j) {
    const int e = e0 + j * T;
    if (e < E) esrc[pv[j]] = sv[j];
  }
}

// ---------------- x: f32 -> bf16 plain conversion --------------------------
__global__ __launch_bounds__(256)
void k_conv_x(const float* __restrict__ src, unsigned short* __restrict__ dst, int n4) {
  for (int i = blockIdx.x * blockDim.x + threadIdx.x; i < n4; i += gridDim.x * blockDim.x) {
    const float4 v = *((const float4*)src + i);
    uint2 o;
    o.x = packbf(v.x, v.y);
    o.y = packbf(v.z, v.w);
    *((uint2*)dst + i) = o;
  }
}

// ---------------- weights: f32 -> bf16 packed chunk-major ------------------
// dst idx (bf16 units) = kt64*(Opack*64) + chunk*(Opack*8) + (col+colOff)*8 + j
// holds src[col][kt64*64 + chunk*8 + j], chunk in 0..7.
struct PackJob { const float* src; unsigned short* dst; int O; int K; int colOff; int Opack; };
struct PackJobs { PackJob j[10]; };

__global__ __launch_bounds__(256)
void k_pack_w(PackJobs jobs) {
  const PackJob J = jobs.j[blockIdx.y];
  const int total = J.O * J.K / 2;  // u32 outputs, source-major
  for (int u = blockIdx.x * blockDim.x + threadIdx.x; u < total; u += gridDim.x * blockDim.x) {
    const int e = u * 2;
    const int col = e / J.K;
    const int k = e - col * J.K;
    const int kt = k >> 6, ch = (k >> 3) & 7, j = k & 7;
    const float f0 = J.src[(size_t)col * J.K + k];
    const float f1 = J.src[(size_t)col * J.K + k + 1];
    const int didx = kt * (J.Opack * 64) + ch * (J.Opack * 8) + (col + J.colOff) * 8 + j;
    ((unsigned int*)J.dst)[didx >> 1] = packbf(f0, f1);
  }
}

// ---------------- mean aggregation, bf16 in/out, f32 accum -----------------
static __device__ __forceinline__ void acc_u4(float* acc, const uint4& v) {
  acc[0] += lo16(v.x); acc[1] += hi16(v.x);
  acc[2] += lo16(v.y); acc[3] += hi16(v.y);
  acc[4] += lo16(v.z); acc[5] += hi16(v.z);
  acc[6] += lo16(v.w); acc[7] += hi16(v.w);
}

// K=128: row = 16 uint4; 4 subgroups of 16 lanes; 32-edge batches.
__global__ __launch_bounds__(256)
void k_agg128(const unsigned short* __restrict__ h, const int* __restrict__ row_off,
              const int* __restrict__ esrc, const float* __restrict__ deg_inv,
              unsigned short* __restrict__ agg, int N) {
  const int node = blockIdx.x * 4 + (threadIdx.x >> 6);
  if (node >= N) return;
  const int lane = threadIdx.x & 63;
  const int g = lane >> 4, c = lane & 15;
  const int s0 = row_off[node], s1 = row_off[node + 1];
  const uint4* hp = (const uint4*)h;
  float acc[8] = {0.f, 0.f, 0.f, 0.f, 0.f, 0.f, 0.f, 0.f};
  for (int i = s0; i < s1; i += 32) {
    int el = i + (lane & 31);
    if (el >= s1) el = s1 - 1;
    const int ev = esrc[el];
    uint4 v[8];
#pragma unroll
    for (int u = 0; u < 8; ++u) {
      if (i + u * 4 < s1) {                        // wave-uniform
        const int e = __shfl(ev, u * 4 + g);
        v[u] = hp[(size_t)e * 16 + c];
      }
    }
#pragma unroll
    for (int u = 0; u < 8; ++u)
      if (i + u * 4 + g < s1) acc_u4(acc, v[u]);
  }
#pragma unroll
  for (int j = 0; j < 8; ++j) {
    acc[j] += __shfl_xor(acc[j], 16);
    acc[j] += __shfl_xor(acc[j], 32);
  }
  if (g == 0) {
    const float di = deg_inv[node];
    uint4 o;
    o.x = packbf(acc[0] * di, acc[1] * di);
    o.y = packbf(acc[2] * di, acc[3] * di);
    o.z = packbf(acc[4] * di, acc[5] * di);
    o.w = packbf(acc[6] * di, acc[7] * di);
    ((uint4*)agg)[(size_t)node * 16 + c] = o;
  }
}

// K=256: row = 32 uint4; 2 subgroups of 32 lanes; 32-edge batches.
__global__ __launch_bounds__(256)
void k_agg256(const unsigned short* __restrict__ h, const int* __restrict__ row_off,
              const int* __restrict__ esrc, const float* __restrict__ deg_inv,
              unsigned short* __restrict__ agg, int N) {
  const int node = blockIdx.x * 4 + (threadIdx.x >> 6);
  if (node >= N) return;
  const int lane = threadIdx.x & 63;
  const int g = lane >> 5, c = lane & 31;
  const int s0 = row_off[node], s1 = row_off[node + 1];
  const uint4* hp = (const uint4*)h;
  float acc[8] = {0.f, 0.f, 0.f, 0.f, 0.f, 0.f, 0.f, 0.f};
  for (int i = s0; i < s1; i += 32) {
    int el = i + (lane & 31);
    if (el >= s1) el = s1 - 1;
    const int ev = esrc[el];
    uint4 v[16];
#pragma unroll
    for (int u = 0; u < 16; ++u) {
      if (i + u * 2 < s1) {                        // wave-uniform
        const int e = __shfl(ev, u * 2 + g);
        v[u] = hp[(size_t)e * 32 + c];
      }
    }
#pragma unroll
    for (int u = 0; u < 16; ++u)
      if (i + u * 2 + g < s1) acc_u4(acc, v[u]);
  }
#pragma unroll
  for (int j = 0; j < 8; ++j) acc[j] += __shfl_xor(acc[j], 32);
  if (g == 0) {
    const float di = deg_inv[node];
    uint4 o;
    o.x = packbf(acc[0] * di, acc[1] * di);
    o.y = packbf(acc[2] * di, acc[3] * di);
    o.z = packbf(acc[4] * di, acc[5] * di);
    o.w = packbf(acc[6] * di, acc[7] * di);
    ((uint4*)agg)[(size_t)node * 32 + c] = o;
  }
}

// K=64: row = 8 uint4; 8 subgroups of 8 lanes; 32-edge batches.
__global__ __launch_bounds__(256)
void k_agg64(const unsigned short* __restrict__ h, const int* __restrict__ row_off,
             const int* __restrict__ esrc, const float* __restrict__ deg_inv,
             unsigned short* __restrict__ agg, int N) {
  const int node = blockIdx.x * 4 + (threadIdx.x >> 6);
  if (node >= N) return;
  const int lane = threadIdx.x & 63;
  const int g = lane >> 3, c = lane & 7;
  const int s0 = row_off[node], s1 = row_off[node + 1];
  const uint4* hp = (const uint4*)h;
  float acc[8] = {0.f, 0.f, 0.f, 0.f, 0.f, 0.f, 0.f, 0.f};
  for (int i = s0; i < s1; i += 32) {
    int el = i + (lane & 31);
    if (el >= s1) el = s1 - 1;
    const int ev = esrc[el];
    uint4 v[4];
#pragma unroll
    for (int u = 0; u < 4; ++u) {
      if (i + u * 8 < s1) {                        // wave-uniform
        const int e = __shfl(ev, u * 8 + g);
        v[u] = hp[(size_t)e * 8 + c];
      }
    }
#pragma unroll
    for (int u = 0; u < 4; ++u)
      if (i + u * 8 + g < s1) acc_u4(acc, v[u]);
  }
#pragma unroll
  for (int j = 0; j < 8; ++j) {
    acc[j] += __shfl_xor(acc[j], 8);
    acc[j] += __shfl_xor(acc[j], 16);
    acc[j] += __shfl_xor(acc[j], 32);
  }
  if (g == 0) {
    const float di = deg_inv[node];
    uint4 o;
    o.x = packbf(acc[0] * di, acc[1] * di);
    o.y = packbf(acc[2] * di, acc[3] * di);
    o.z = packbf(acc[4] * di, acc[5] * di);
    o.w = packbf(acc[6] * di, acc[7] * di);
    ((uint4*)agg)[(size_t)node * 8 + c] = o;
  }
}

// L1 fused post-transform aggregate: z = [Zl | Yr] (N x 128 bf16).
// out[n][0..63] = relu(deg_inv[n] * sum_e Zl[src(e)] + Yr[n] + bias).
__global__ __launch_bounds__(256)
void k_agg_post64(const unsigned short* __restrict__ z, const int* __restrict__ row_off,
                  const int* __restrict__ esrc, const float* __restrict__ deg_inv,
                  const float* __restrict__ bias, unsigned short* __restrict__ out, int N) {
  const int node = blockIdx.x * 4 + (threadIdx.x >> 6);
  if (node >= N) return;
  const int lane = threadIdx.x & 63;
  const int g = lane >> 3, c = lane & 7;
  const int s0 = row_off[node], s1 = row_off[node + 1];
  const uint4* zp = (const uint4*)z;   // row = 16 uint4; Zl = first 8
  float acc[8] = {0.f, 0.f, 0.f, 0.f, 0.f, 0.f, 0.f, 0.f};
  for (int i = s0; i < s1; i += 32) {
    int el = i + (lane & 31);
    if (el >= s1) el = s1 - 1;
    const int ev = esrc[el];
    uint4 v[4];
#pragma unroll
    for (int u = 0; u < 4; ++u) {
      if (i + u * 8 < s1) {
        const int e = __shfl(ev, u * 8 + g);
        v[u] = zp[(size_t)e * 16 + c];
      }
    }
#pragma unroll
    for (int u = 0; u < 4; ++u)
      if (i + u * 8 + g < s1) acc_u4(acc, v[u]);
  }
#pragma unroll
  for (int j = 0; j < 8; ++j) {
    acc[j] += __shfl_xor(acc[j], 8);
    acc[j] += __shfl_xor(acc[j], 16);
    acc[j] += __shfl_xor(acc[j], 32);
  }
  if (g == 0) {
    const float di = deg_inv[node];
    const uint4 yr = zp[(size_t)node * 16 + 8 + c];
    float y[8];
    y[0] = lo16(yr.x); y[1] = hi16(yr.x); y[2] = lo16(yr.y); y[3] = hi16(yr.y);
    y[4] = lo16(yr.z); y[5] = hi16(yr.z); y[6] = lo16(yr.w); y[7] = hi16(yr.w);
    float r[8];
#pragma unroll
    for (int j = 0; j < 8; ++j)
      r[j] = fmaxf(acc[j] * di + y[j] + bias[c * 8 + j], 0.f);
    uint4 o;
    o.x = packbf(r[0], r[1]);
    o.y = packbf(r[2], r[3]);
    o.z = packbf(r[4], r[5]);
    o.w = packbf(r[6], r[7]);
    ((uint4*)out)[(size_t)node * 8 + c] = o;
  }
}

// ---------------- fused SAGE GEMM ------------------------------------------
// FUSED=true : C = relu(A0@B0p^T + A1@B1p^T + bias)  (two phases)
// FUSED=false: C = A0@B0p^T                           (single phase, raw)
// Block: 128 rows x BN=WC*64 cols; 2 x WC waves; MFMA 32x32x16; BK=64.
// A staged in LDS (32KB double-buffer -> 5 blocks/CU); B read direct from
// global packed layout; per-tile B loads HOISTED before the MFMA loop.
// 1D grid, XCD-co-located decode: r8=bid&7, cb=(bid>>3)%NCB, rowp=((bid>>3)/NCB)*8+r8
template <int WC, int NCB, bool FUSED>
__global__ __launch_bounds__(WC * 128)
void k_sage_gemm(const unsigned short* __restrict__ A0, const unsigned short* __restrict__ B0,
                 const unsigned short* __restrict__ A1, const unsigned short* __restrict__ B1,
                 const float* __restrict__ bias, unsigned short* __restrict__ C,
                 int Nn, int K, int O) {
  constexpr int BN = WC * 64;
  constexpr int T = WC * 128;
  constexpr int ACH = 1024;            // A 16B-chunks per tile (128 rows x 8)
  constexpr int LPT = ACH / T;         // A chunks per thread per stage
  __shared__ char lds[2 * 16384];

  const int nrp = (Nn + 127) >> 7;
  const int bid = blockIdx.x;
  const int r8 = bid & 7;
  const int tb = bid >> 3;
  const int cb = tb % NCB;
  const int rowp = (tb / NCB) * 8 + r8;
  if (rowp >= nrp) return;

  const int tid = threadIdx.x;
  const int w = tid >> 6, lane = tid & 63;
  const int wr = w / WC, wc = w % WC;
  const int fr = lane & 31, fq = lane >> 5;
  const int row0 = rowp * 128 + wr * 64;
  const int colb = cb * BN;

  const int KT0 = K >> 6;        // 64-wide tiles per phase
  const int NT = FUSED ? 2 * KT0 : KT0;

  f32x16 acc[2][2];
#pragma unroll
  for (int m = 0; m < 2; ++m)
#pragma unroll
    for (int cn = 0; cn < 2; ++cn)
#pragma unroll
      for (int r = 0; r < 16; ++r) acc[m][cn][r] = 0.f;

  auto stage = [&](int buf, int t) {
    const unsigned short* Ab;
    int ktl;
    if (FUSED) {
      const int ph = (t >= KT0) ? 1 : 0;
      Ab = ph ? A1 : A0;
      ktl = t - ph * KT0;
    } else {
      Ab = A0; ktl = t;
    }
    char* lb = lds + buf * 16384;
#pragma unroll
    for (int i = 0; i < LPT; ++i) {
      const int ch = tid + i * T;
      const int ar = ch >> 3, s = ch & 7;           // LDS row, slot
      int g = rowp * 128 + ar;
      if (g >= Nn) g = Nn - 1;
      // inverse-swizzled global source; linear LDS dest
      gl_lds16(Ab + (size_t)g * K + ktl * 64 + ((s ^ (ar & 7)) << 3), lb + ch * 16);
    }
  };

  stage(0, 0);
#pragma unroll 1
  for (int t = 0; t < NT; ++t) {
    asm volatile("s_waitcnt vmcnt(0)" ::: "memory");
    __syncthreads();
    // B pointer for this tile (global, packed chunk-major)
    const unsigned short* Bp;
    int ktl;
    if (FUSED) {
      const int ph = (t >= KT0) ? 1 : 0;
      Bp = ph ? B1 : B0;
      ktl = t - ph * KT0;
    } else {
      Bp = B0; ktl = t;
    }
    const unsigned short* Bbase = Bp + (size_t)ktl * (O * 64) + (size_t)(colb + wc * 64) * 8;
    // HOIST: issue all 8 B loads for this tile up front (oldest in queue)
    bf16x8 bg[4][2];
#pragma unroll
    for (int k16i = 0; k16i < 4; ++k16i) {
      const int c = k16i * 2 + fq;                  // chunk 0..7
#pragma unroll
      for (int cn = 0; cn < 2; ++cn)
        bg[k16i][cn] = *(const bf16x8*)(Bbase + (size_t)c * (O * 8) + (cn * 32 + fr) * 8);
    }
    if (t + 1 < NT) stage((t + 1) & 1, t + 1);
    const char* lb = lds + (t & 1) * 16384;
#pragma unroll
    for (int k16i = 0; k16i < 4; ++k16i) {
      const int c = k16i * 2 + fq;                  // chunk 0..7
      bf16x8 af[2];
#pragma unroll
      for (int m = 0; m < 2; ++m) {
        const int rl = wr * 64 + m * 32 + fr;
        af[m] = *(const bf16x8*)(lb + rl * 128 + ((c ^ (rl & 7)) << 4));
      }
#pragma unroll
      for (int m = 0; m < 2; ++m)
#pragma unroll
        for (int cn = 0; cn < 2; ++cn)
          acc[m][cn] = __builtin_amdgcn_mfma_f32_32x32x16_bf16(af[m], bg[k16i][cn], acc[m][cn], 0, 0, 0);
    }
  }

  // epilogue. C/D map: col = lane&31, row = (reg&3) + 8*(reg>>2) + 4*(lane>>5).
#pragma unroll
  for (int cn = 0; cn < 2; ++cn) {
    const int col = colb + wc * 64 + cn * 32 + fr;
    float bb = 0.f;
    if (FUSED) bb = bias[col];
#pragma unroll
    for (int m = 0; m < 2; ++m) {
#pragma unroll
      for (int reg = 0; reg < 16; ++reg) {
        float v = acc[m][cn][reg];
        if (FUSED) v = fmaxf(v + bb, 0.f);
        const float nb = __shfl_xor(v, 1);
        const int row = row0 + m * 32 + (reg & 3) + 8 * (reg >> 2) + 4 * fq;
        if (!(lane & 1) && row < Nn) {
          *(unsigned int*)(C + (size_t)row * O + col) = packbf(v, nb);
        }
      }
    }
  }
}

// ---------------- head: logits(512->4) + softmax, 4 waves per block --------
// W4 (2048 f32 = 8KB) staged in LDS once per block.
__global__ __launch_bounds__(256)
void k_out_softmax(const unsigned short* __restrict__ h, const float* __restrict__ W4,
                   const float* __restrict__ b, float* __restrict__ out, int N) {
  __shared__ float w[2048];
  const int tid = threadIdx.x;
#pragma unroll
  for (int i = 0; i < 8; ++i) w[tid + i * 256] = W4[tid + i * 256];
  __syncthreads();
  const int n = blockIdx.x * 4 + (tid >> 6);
  if (n >= N) return;
  const int lane = tid & 63;
  const unsigned int* hp = (const unsigned int*)h + (size_t)n * 256;
  float a[4] = {0.f, 0.f, 0.f, 0.f};
#pragma unroll
  for (int it = 0; it < 4; ++it) {
    const unsigned int v = hp[it * 64 + lane];
    const float lo = lo16(v);
    const float hi = hi16(v);
    const int k = (it * 64 + lane) * 2;
#pragma unroll
    for (int c = 0; c < 4; ++c)
      a[c] += lo * w[c * 512 + k] + hi * w[c * 512 + k + 1];
  }
#pragma unroll
  for (int off = 32; off > 0; off >>= 1) {
#pragma unroll
    for (int c = 0; c < 4; ++c) a[c] += __shfl_down(a[c], off);
  }
  if (lane == 0) {
    const float l0 = a[0] + b[0], l1 = a[1] + b[1], l2 = a[2] + b[2], l3 = a[3] + b[3];
    const float m = fmaxf(fmaxf(l0, l1), fmaxf(l2, l3));
    const float e0 = expf(l0 - m), e1 = expf(l1 - m), e2 = expf(l2 - m), e3 = expf(l3 - m);
    const float inv = 1.0f / (e0 + e1 + e2 + e3);
    float4 r; r.x = e0 * inv; r.y = e1 * inv; r.z = e2 * inv; r.w = e3 * inv;
    *(float4*)(out + (size_t)n * 4) = r;
  }
}

// ---------------------------------------------------------------------------
extern "C" void kernel_launch(void* const* d_in, const int* in_sizes, int n_in,
                              void* d_out, int out_size, void* d_ws, size_t ws_size,
                              hipStream_t stream) {
  const float* x = (const float*)d_in[0];
  const float* Wl[5] = {(const float*)d_in[1], (const float*)d_in[4], (const float*)d_in[7],
                        (const float*)d_in[10], (const float*)d_in[13]};
  const float* bl[5] = {(const float*)d_in[2], (const float*)d_in[5], (const float*)d_in[8],
                        (const float*)d_in[11], (const float*)d_in[14]};
  const float* Wr[5] = {(const float*)d_in[3], (const float*)d_in[6], (const float*)d_in[9],
                        (const float*)d_in[12], (const float*)d_in[15]};
  const float* Wout = (const float*)d_in[16];
  const float* bout = (const float*)d_in[17];
  const int* eidx = (const int*)d_in[18];

  const int N = in_sizes[0] / 128;
  const int E = in_sizes[18] / 2;
  const int* srcI = eidx;
  const int* dstI = eidx + E;

  const int Kd[5] = {128, 128, 64, 128, 256};
  const int Od[5] = {128, 64, 128, 256, 512};

  // workspace carve-out (256B aligned)
  char* ws = (char*)d_ws;
  size_t p = 0;
  auto alloc = [&](size_t bytes) { size_t r = p; p += (bytes + 255) & ~(size_t)255; return r; };
  int*   deg     = (int*)(ws + alloc((size_t)N * 4));
  int*   row_off = (int*)(ws + alloc((size_t)(N + 1) * 4));
  int*   cursor  = (int*)(ws + alloc((size_t)N * 4));
  float* deg_inv = (float*)(ws + alloc((size_t)N * 4));
  int*   loc     = (int*)(ws + alloc((size_t)N * 4));
  int*   part    = (int*)(ws + alloc((size_t)1032 * 4));
  int*   esrc    = (int*)(ws + alloc((size_t)E * 4));
  unsigned short* xb = (unsigned short*)(ws + alloc((size_t)N * 128 * 2));
  unsigned short* wlb[5];
  unsigned short* wrb[5];
  for (int l = 0; l < 5; ++l) {
    wlb[l] = (unsigned short*)(ws + alloc((size_t)Od[l] * Kd[l] * 2));
    wrb[l] = (unsigned short*)(ws + alloc((size_t)Od[l] * Kd[l] * 2));
  }
  unsigned short* wcat1 = (unsigned short*)(ws + alloc((size_t)128 * 128 * 2));
  unsigned short* bufA = (unsigned short*)(ws + alloc((size_t)N * 512 * 2));
  unsigned short* bufB = (unsigned short*)(ws + alloc((size_t)N * 256 * 2));
  unsigned short* agg  = (unsigned short*)(ws + alloc((size_t)N * 256 * 2));
  (void)ws_size; (void)n_in; (void)out_size;

  // ---- conversions: x plain; weights packed chunk-major ----
  k_conv_x<<<128, 256, 0, stream>>>(x, xb, N * 128 / 4);
  PackJobs jobs;
  for (int l = 0; l < 5; ++l) {
    if (l == 1) {
      jobs.j[2] = {Wl[1], wcat1, 64, 128, 0, 128};   // Zl cols 0..63
      jobs.j[3] = {Wr[1], wcat1, 64, 128, 64, 128};  // Yr cols 64..127
    } else {
      jobs.j[2 * l]     = {Wl[l], wlb[l], Od[l], Kd[l], 0, Od[l]};
      jobs.j[2 * l + 1] = {Wr[l], wrb[l], Od[l], Kd[l], 0, Od[l]};
    }
  }
  k_pack_w<<<dim3(32, 10), 256, 0, stream>>>(jobs);

  // ---- CSR build (multi-block scan; x8-batched atomics) ----
  hipMemsetAsync(deg, 0, (size_t)N * 4, stream);
  k_count_deg<<<idiv_up(E, 2048), 256, 0, stream>>>(dstI, deg, E);
  const int nb = idiv_up(N, 1024);
  k_scan1<<<nb, 1024, 0, stream>>>(deg, loc, part, N);
  k_scan2<<<1, 1024, 0, stream>>>(part, nb);
  k_scan3<<<idiv_up(N + 1, 256), 256, 0, stream>>>(deg, loc, part, row_off, cursor, deg_inv, N, nb);
  k_fill_csr<<<idiv_up(E, 2048), 256, 0, stream>>>(srcI, dstI, cursor, esrc, E);

  const int gx8 = 8 * ((idiv_up(N, 128) + 7) / 8);   // padded row-panel grid

  // ---- layer 0: K=128, O=128 ----
  k_agg128<<<idiv_up(N, 4), 256, 0, stream>>>(xb, row_off, esrc, deg_inv, agg, N);
  k_sage_gemm<2, 1, true><<<gx8, 256, 0, stream>>>(agg, wlb[0], xb, wrb[0], bl[0], bufA, N, 128, 128);

  // ---- layer 1 (linearity swap): Z|Yr = h1 @ [Wl;Wr]^T, then fused agg ----
  k_sage_gemm<2, 1, false><<<gx8, 256, 0, stream>>>(bufA, wcat1, bufA, wcat1, bl[1], agg, N, 128, 128);
  k_agg_post64<<<idiv_up(N, 4), 256, 0, stream>>>(agg, row_off, esrc, deg_inv, bl[1], bufB, N);

  // ---- layer 2: K=64, O=128 ----
  k_agg64<<<idiv_up(N, 4), 256, 0, stream>>>(bufB, row_off, esrc, deg_inv, agg, N);
  k_sage_gemm<2, 1, true><<<gx8, 256, 0, stream>>>(agg, wlb[2], bufB, wrb[2], bl[2], bufA, N, 64, 128);

  // ---- layer 3: K=128, O=256 (2 col-blocks, XCD-co-located) ----
  k_agg128<<<idiv_up(N, 4), 256, 0, stream>>>(bufA, row_off, esrc, deg_inv, agg, N);
  k_sage_gemm<2, 2, true><<<2 * gx8, 256, 0, stream>>>(agg, wlb[3], bufA, wrb[3], bl[3], bufB, N, 128, 256);

  // ---- layer 4: K=256, O=512 (4 col-blocks, XCD-co-located) ----
  k_agg256<<<idiv_up(N, 4), 256, 0, stream>>>(bufB, row_off, esrc, deg_inv, agg, N);
  k_sage_gemm<2, 4, true><<<4 * gx8, 256, 0, stream>>>(agg, wlb[4], bufB, wrb[4], bl[4], bufA, N, 256, 512);

  k_out_softmax<<<idiv_up(N, 4), 256, 0, stream>>>(bufA, Wout, bout, (float*)d_out, N);
}

// Round 17
// 392.805 us; speedup vs baseline: 1.1445x; 1.0018x over previous
//
#include <hip/hip_runtime.h>
#include <hip/hip_bf16.h>
#include <cstdint>
#include <cstddef>

// ---------------------------------------------------------------------------
// SAGE GNN forward, bf16 MFMA 32x32x16, LDS-staged GEMM, BK=64.
//  - GEMM: 3-buffer A-pipeline with RAW s_barrier + counted per-wave
//    vmcnt(4) (A staged 2 tiles ahead; __syncthreads' vmcnt(0) drain removed).
//    B direct from global (packed), per-tile B loads hoisted. Epilogue simple.
//  - L1: linearity swap; aggregates: 32-edge shfl batches; CSR: x8 atomics.
// ---------------------------------------------------------------------------

typedef short bf16x8 __attribute__((ext_vector_type(8)));   // 8 bf16 = 4 VGPRs
typedef float f32x16 __attribute__((ext_vector_type(16)));

static inline int idiv_up(int a, int b) { return (a + b - 1) / b; }

static __device__ __forceinline__ float bf2f(unsigned short u) {
  union { unsigned int i; float f; } v; v.i = ((unsigned int)u) << 16; return v.f;
}
static __device__ __forceinline__ unsigned short f2bf(float f) {
  union { float f; unsigned int i; } v; v.f = f;
  return (unsigned short)((v.i + 0x7FFFu + ((v.i >> 16) & 1u)) >> 16);  // RNE
}
static __device__ __forceinline__ float lo16(unsigned int u) { return bf2f((unsigned short)(u & 0xffffu)); }
static __device__ __forceinline__ float hi16(unsigned int u) { return bf2f((unsigned short)(u >> 16)); }
static __device__ __forceinline__ unsigned int packbf(float a, float b) {
  return (unsigned int)f2bf(a) | ((unsigned int)f2bf(b) << 16);
}

// async global->LDS, 16B per lane. LDS dest: wave-uniform base + lane*16.
static __device__ __forceinline__ void gl_lds16(const void* g, void* l) {
  typedef __attribute__((address_space(3))) unsigned int lds_u32;
  typedef __attribute__((address_space(1))) const unsigned int glb_u32;
  __builtin_amdgcn_global_load_lds((glb_u32*)(uintptr_t)g,
                                   (lds_u32*)(unsigned int)(uintptr_t)l, 16, 0, 0);
}

// ---------------- CSR build ----------------
// x8 edges per thread (strided): 8 independent atomics in flight per thread.
__global__ void k_count_deg(const int* __restrict__ dst, int* __restrict__ deg, int E) {
  const int T = gridDim.x * blockDim.x;
  const int e0 = blockIdx.x * blockDim.x + threadIdx.x;
#pragma unroll
  for (int j = 0; j < 8; ++j) {
    const int e = e0 + j * T;
    if (e < E) atomicAdd(deg + dst[e], 1);
  }
}

// pass 1: per-1024-block inclusive scan -> loc; block total -> part[bid]
__global__ __launch_bounds__(1024)
void k_scan1(const int* __restrict__ deg, int* __restrict__ loc, int* __restrict__ part, int n) {
  __shared__ int wsum[16];
  const int tid = threadIdx.x;
  const int lane = tid & 63, wid = tid >> 6;
  const int i = blockIdx.x * 1024 + tid;
  const int v = (i < n) ? deg[i] : 0;
  int incl = v;
#pragma unroll
  for (int off = 1; off < 64; off <<= 1) {
    int t = __shfl_up(incl, off);
    if (lane >= off) incl += t;
  }
  if (lane == 63) wsum[wid] = incl;
  __syncthreads();
  if (wid == 0) {
    int wv = (lane < 16) ? wsum[lane] : 0;
#pragma unroll
    for (int off = 1; off < 16; off <<= 1) {
      int t = __shfl_up(wv, off);
      if (lane >= off) wv += t;
    }
    if (lane < 16) wsum[lane] = wv;
  }
  __syncthreads();
  const int woff = (wid > 0) ? wsum[wid - 1] : 0;
  if (i < n) loc[i] = woff + incl;      // inclusive within block
  if (tid == 1023) part[blockIdx.x] = woff + incl;
}

// pass 2: single block scans nb (<=1024) partials -> exclusive; part[nb]=total
__global__ __launch_bounds__(1024)
void k_scan2(int* __restrict__ part, int nb) {
  __shared__ int wsum[16];
  const int tid = threadIdx.x;
  const int lane = tid & 63, wid = tid >> 6;
  const int v = (tid < nb) ? part[tid] : 0;
  int incl = v;
#pragma unroll
  for (int off = 1; off < 64; off <<= 1) {
    int t = __shfl_up(incl, off);
    if (lane >= off) incl += t;
  }
  if (lane == 63) wsum[wid] = incl;
  __syncthreads();
  if (wid == 0) {
    int wv = (lane < 16) ? wsum[lane] : 0;
#pragma unroll
    for (int off = 1; off < 16; off <<= 1) {
      int t = __shfl_up(wv, off);
      if (lane >= off) wv += t;
    }
    if (lane < 16) wsum[lane] = wv;
  }
  __syncthreads();
  const int woff = (wid > 0) ? wsum[wid - 1] : 0;
  if (tid < nb) part[tid] = woff + incl - v;  // exclusive
  if (tid == 0) part[nb] = wsum[15];          // total
}

// pass 3: apply offsets; emit row_off / cursor / deg_inv
__global__ __launch_bounds__(256)
void k_scan3(const int* __restrict__ deg, const int* __restrict__ loc, const int* __restrict__ part,
             int* __restrict__ row_off, int* __restrict__ cursor, float* __restrict__ deg_inv,
             int n, int nb) {
  const int i = blockIdx.x * blockDim.x + threadIdx.x;
  if (i < n) {
    const int v = deg[i];
    const int ro = part[i >> 10] + loc[i] - v;
    row_off[i] = ro;
    cursor[i] = ro;
    deg_inv[i] = 1.0f / (float)((v > 1) ? v : 1);
  }
  if (i == 0) row_off[n] = part[nb];
}

// x8 edges per thread: gather inputs, 8 independent atomic-returns, 8 stores.
__global__ void k_fill_csr(const int* __restrict__ src, const int* __restrict__ dst,
                           int* __restrict__ cursor, int* __restrict__ esrc, int E) {
  const int T = gridDim.x * blockDim.x;
  const int e0 = blockIdx.x * blockDim.x + threadIdx.x;
  int dv[8], sv[8], pv[8];
#pragma unroll
  for (int j = 0; j < 8; ++j) {
    const int e = e0 + j * T;
    if (e < E) { dv[j] = dst[e]; sv[j] = src[e]; }
  }
#pragma unroll
  for (int j = 0; j < 8; ++j) {
    const int e = e0 + j * T;
    if (e < E) pv[j] = atomicAdd(cursor + dv[j], 1);
  }
#pragma unroll
  for (int j = 0; j < 8; ++j) {
    const int e = e0 + j * T;
    if (e < E) esrc[pv[j]] = sv[j];
  }
}

// ---------------- x: f32 -> bf16 plain conversion --------------------------
__global__ __launch_bounds__(256)
void k_conv_x(const float* __restrict__ src, unsigned short* __restrict__ dst, int n4) {
  for (int i = blockIdx.x * blockDim.x + threadIdx.x; i < n4; i += gridDim.x * blockDim.x) {
    const float4 v = *((const float4*)src + i);
    uint2 o;
    o.x = packbf(v.x, v.y);
    o.y = packbf(v.z, v.w);
    *((uint2*)dst + i) = o;
  }
}

// ---------------- weights: f32 -> bf16 packed chunk-major ------------------
// dst idx (bf16 units) = kt64*(Opack*64) + chunk*(Opack*8) + (col+colOff)*8 + j
// holds src[col][kt64*64 + chunk*8 + j], chunk in 0..7.
struct PackJob { const float* src; unsigned short* dst; int O; int K; int colOff; int Opack; };
struct PackJobs { PackJob j[10]; };

__global__ __launch_bounds__(256)
void k_pack_w(PackJobs jobs) {
  const PackJob J = jobs.j[blockIdx.y];
  const int total = J.O * J.K / 2;  // u32 outputs, source-major
  for (int u = blockIdx.x * blockDim.x + threadIdx.x; u < total; u += gridDim.x * blockDim.x) {
    const int e = u * 2;
    const int col = e / J.K;
    const int k = e - col * J.K;
    const int kt = k >> 6, ch = (k >> 3) & 7, j = k & 7;
    const float f0 = J.src[(size_t)col * J.K + k];
    const float f1 = J.src[(size_t)col * J.K + k + 1];
    const int didx = kt * (J.Opack * 64) + ch * (J.Opack * 8) + (col + J.colOff) * 8 + j;
    ((unsigned int*)J.dst)[didx >> 1] = packbf(f0, f1);
  }
}

// ---------------- mean aggregation, bf16 in/out, f32 accum -----------------
static __device__ __forceinline__ void acc_u4(float* acc, const uint4& v) {
  acc[0] += lo16(v.x); acc[1] += hi16(v.x);
  acc[2] += lo16(v.y); acc[3] += hi16(v.y);
  acc[4] += lo16(v.z); acc[5] += hi16(v.z);
  acc[6] += lo16(v.w); acc[7] += hi16(v.w);
}

// K=128: row = 16 uint4; 4 subgroups of 16 lanes; 32-edge batches.
__global__ __launch_bounds__(256)
void k_agg128(const unsigned short* __restrict__ h, const int* __restrict__ row_off,
              const int* __restrict__ esrc, const float* __restrict__ deg_inv,
              unsigned short* __restrict__ agg, int N) {
  const int node = blockIdx.x * 4 + (threadIdx.x >> 6);
  if (node >= N) return;
  const int lane = threadIdx.x & 63;
  const int g = lane >> 4, c = lane & 15;
  const int s0 = row_off[node], s1 = row_off[node + 1];
  const uint4* hp = (const uint4*)h;
  float acc[8] = {0.f, 0.f, 0.f, 0.f, 0.f, 0.f, 0.f, 0.f};
  for (int i = s0; i < s1; i += 32) {
    int el = i + (lane & 31);
    if (el >= s1) el = s1 - 1;
    const int ev = esrc[el];
    uint4 v[8];
#pragma unroll
    for (int u = 0; u < 8; ++u) {
      if (i + u * 4 < s1) {                        // wave-uniform
        const int e = __shfl(ev, u * 4 + g);
        v[u] = hp[(size_t)e * 16 + c];
      }
    }
#pragma unroll
    for (int u = 0; u < 8; ++u)
      if (i + u * 4 + g < s1) acc_u4(acc, v[u]);
  }
#pragma unroll
  for (int j = 0; j < 8; ++j) {
    acc[j] += __shfl_xor(acc[j], 16);
    acc[j] += __shfl_xor(acc[j], 32);
  }
  if (g == 0) {
    const float di = deg_inv[node];
    uint4 o;
    o.x = packbf(acc[0] * di, acc[1] * di);
    o.y = packbf(acc[2] * di, acc[3] * di);
    o.z = packbf(acc[4] * di, acc[5] * di);
    o.w = packbf(acc[6] * di, acc[7] * di);
    ((uint4*)agg)[(size_t)node * 16 + c] = o;
  }
}

// K=256: row = 32 uint4; 2 subgroups of 32 lanes; 32-edge batches.
__global__ __launch_bounds__(256)
void k_agg256(const unsigned short* __restrict__ h, const int* __restrict__ row_off,
              const int* __restrict__ esrc, const float* __restrict__ deg_inv,
              unsigned short* __restrict__ agg, int N) {
  const int node = blockIdx.x * 4 + (threadIdx.x >> 6);
  if (node >= N) return;
  const int lane = threadIdx.x & 63;
  const int g = lane >> 5, c = lane & 31;
  const int s0 = row_off[node], s1 = row_off[node + 1];
  const uint4* hp = (const uint4*)h;
  float acc[8] = {0.f, 0.f, 0.f, 0.f, 0.f, 0.f, 0.f, 0.f};
  for (int i = s0; i < s1; i += 32) {
    int el = i + (lane & 31);
    if (el >= s1) el = s1 - 1;
    const int ev = esrc[el];
    uint4 v[16];
#pragma unroll
    for (int u = 0; u < 16; ++u) {
      if (i + u * 2 < s1) {                        // wave-uniform
        const int e = __shfl(ev, u * 2 + g);
        v[u] = hp[(size_t)e * 32 + c];
      }
    }
#pragma unroll
    for (int u = 0; u < 16; ++u)
      if (i + u * 2 + g < s1) acc_u4(acc, v[u]);
  }
#pragma unroll
  for (int j = 0; j < 8; ++j) acc[j] += __shfl_xor(acc[j], 32);
  if (g == 0) {
    const float di = deg_inv[node];
    uint4 o;
    o.x = packbf(acc[0] * di, acc[1] * di);
    o.y = packbf(acc[2] * di, acc[3] * di);
    o.z = packbf(acc[4] * di, acc[5] * di);
    o.w = packbf(acc[6] * di, acc[7] * di);
    ((uint4*)agg)[(size_t)node * 32 + c] = o;
  }
}

// K=64: row = 8 uint4; 8 subgroups of 8 lanes; 32-edge batches.
__global__ __launch_bounds__(256)
void k_agg64(const unsigned short* __restrict__ h, const int* __restrict__ row_off,
             const int* __restrict__ esrc, const float* __restrict__ deg_inv,
             unsigned short* __restrict__ agg, int N) {
  const int node = blockIdx.x * 4 + (threadIdx.x >> 6);
  if (node >= N) return;
  const int lane = threadIdx.x & 63;
  const int g = lane >> 3, c = lane & 7;
  const int s0 = row_off[node], s1 = row_off[node + 1];
  const uint4* hp = (const uint4*)h;
  float acc[8] = {0.f, 0.f, 0.f, 0.f, 0.f, 0.f, 0.f, 0.f};
  for (int i = s0; i < s1; i += 32) {
    int el = i + (lane & 31);
    if (el >= s1) el = s1 - 1;
    const int ev = esrc[el];
    uint4 v[4];
#pragma unroll
    for (int u = 0; u < 4; ++u) {
      if (i + u * 8 < s1) {                        // wave-uniform
        const int e = __shfl(ev, u * 8 + g);
        v[u] = hp[(size_t)e * 8 + c];
      }
    }
#pragma unroll
    for (int u = 0; u < 4; ++u)
      if (i + u * 8 + g < s1) acc_u4(acc, v[u]);
  }
#pragma unroll
  for (int j = 0; j < 8; ++j) {
    acc[j] += __shfl_xor(acc[j], 8);
    acc[j] += __shfl_xor(acc[j], 16);
    acc[j] += __shfl_xor(acc[j], 32);
  }
  if (g == 0) {
    const float di = deg_inv[node];
    uint4 o;
    o.x = packbf(acc[0] * di, acc[1] * di);
    o.y = packbf(acc[2] * di, acc[3] * di);
    o.z = packbf(acc[4] * di, acc[5] * di);
    o.w = packbf(acc[6] * di, acc[7] * di);
    ((uint4*)agg)[(size_t)node * 8 + c] = o;
  }
}

// L1 fused post-transform aggregate: z = [Zl | Yr] (N x 128 bf16).
// out[n][0..63] = relu(deg_inv[n] * sum_e Zl[src(e)] + Yr[n] + bias).
__global__ __launch_bounds__(256)
void k_agg_post64(const unsigned short* __restrict__ z, const int* __restrict__ row_off,
                  const int* __restrict__ esrc, const float* __restrict__ deg_inv,
                  const float* __restrict__ bias, unsigned short* __restrict__ out, int N) {
  const int node = blockIdx.x * 4 + (threadIdx.x >> 6);
  if (node >= N) return;
  const int lane = threadIdx.x & 63;
  const int g = lane >> 3, c = lane & 7;
  const int s0 = row_off[node], s1 = row_off[node + 1];
  const uint4* zp = (const uint4*)z;   // row = 16 uint4; Zl = first 8
  float acc[8] = {0.f, 0.f, 0.f, 0.f, 0.f, 0.f, 0.f, 0.f};
  for (int i = s0; i < s1; i += 32) {
    int el = i + (lane & 31);
    if (el >= s1) el = s1 - 1;
    const int ev = esrc[el];
    uint4 v[4];
#pragma unroll
    for (int u = 0; u < 4; ++u) {
      if (i + u * 8 < s1) {
        const int e = __shfl(ev, u * 8 + g);
        v[u] = zp[(size_t)e * 16 + c];
      }
    }
#pragma unroll
    for (int u = 0; u < 4; ++u)
      if (i + u * 8 + g < s1) acc_u4(acc, v[u]);
  }
#pragma unroll
  for (int j = 0; j < 8; ++j) {
    acc[j] += __shfl_xor(acc[j], 8);
    acc[j] += __shfl_xor(acc[j], 16);
    acc[j] += __shfl_xor(acc[j], 32);
  }
  if (g == 0) {
    const float di = deg_inv[node];
    const uint4 yr = zp[(size_t)node * 16 + 8 + c];
    float y[8];
    y[0] = lo16(yr.x); y[1] = hi16(yr.x); y[2] = lo16(yr.y); y[3] = hi16(yr.y);
    y[4] = lo16(yr.z); y[5] = hi16(yr.z); y[6] = lo16(yr.w); y[7] = hi16(yr.w);
    float r[8];
#pragma unroll
    for (int j = 0; j < 8; ++j)
      r[j] = fmaxf(acc[j] * di + y[j] + bias[c * 8 + j], 0.f);
    uint4 o;
    o.x = packbf(r[0], r[1]);
    o.y = packbf(r[2], r[3]);
    o.z = packbf(r[4], r[5]);
    o.w = packbf(r[6], r[7]);
    ((uint4*)out)[(size_t)node * 8 + c] = o;
  }
}

// ---------------- fused SAGE GEMM ------------------------------------------
// 3-buffer A pipeline: A staged TWO tiles ahead; per-tile sync is
//   s_waitcnt vmcnt(4) lgkmcnt(0)  (per-wave: drains own A(t) share, keeps
//   A(t+1) in flight; own ds_reads of t-1 done) ; raw s_barrier ;
//   sched_barrier(0)  (rule 18: pin ds_reads below the wait).
// B read direct from global packed layout, hoisted per tile.
// 1D grid, XCD-co-located decode: r8=bid&7, cb=(bid>>3)%NCB, rowp=((bid>>3)/NCB)*8+r8
template <int WC, int NCB, bool FUSED>
__global__ __launch_bounds__(WC * 128)
void k_sage_gemm(const unsigned short* __restrict__ A0, const unsigned short* __restrict__ B0,
                 const unsigned short* __restrict__ A1, const unsigned short* __restrict__ B1,
                 const float* __restrict__ bias, unsigned short* __restrict__ C,
                 int Nn, int K, int O) {
  constexpr int BN = WC * 64;
  constexpr int T = WC * 128;
  constexpr int ACH = 1024;            // A 16B-chunks per tile (128 rows x 8)
  constexpr int LPT = ACH / T;         // A chunks per thread per stage
  __shared__ char lds[3 * 16384];      // 3-deep A buffers

  const int nrp = (Nn + 127) >> 7;
  const int bid = blockIdx.x;
  const int r8 = bid & 7;
  const int tb = bid >> 3;
  const int cb = tb % NCB;
  const int rowp = (tb / NCB) * 8 + r8;
  if (rowp >= nrp) return;

  const int tid = threadIdx.x;
  const int w = tid >> 6, lane = tid & 63;
  const int wr = w / WC, wc = w % WC;
  const int fr = lane & 31, fq = lane >> 5;
  const int row0 = rowp * 128 + wr * 64;
  const int colb = cb * BN;

  const int KT0 = K >> 6;        // 64-wide tiles per phase
  const int NT = FUSED ? 2 * KT0 : KT0;

  f32x16 acc[2][2];
#pragma unroll
  for (int m = 0; m < 2; ++m)
#pragma unroll
    for (int cn = 0; cn < 2; ++cn)
#pragma unroll
      for (int r = 0; r < 16; ++r) acc[m][cn][r] = 0.f;

  auto stage = [&](int buf, int t) {
    const unsigned short* Ab;
    int ktl;
    if (FUSED) {
      const int ph = (t >= KT0) ? 1 : 0;
      Ab = ph ? A1 : A0;
      ktl = t - ph * KT0;
    } else {
      Ab = A0; ktl = t;
    }
    char* lb = lds + buf * 16384;
#pragma unroll
    for (int i = 0; i < LPT; ++i) {
      const int ch = tid + i * T;
      const int ar = ch >> 3, s = ch & 7;           // LDS row, slot
      int g = rowp * 128 + ar;
      if (g >= Nn) g = Nn - 1;
      // inverse-swizzled global source; linear LDS dest
      gl_lds16(Ab + (size_t)g * K + ktl * 64 + ((s ^ (ar & 7)) << 3), lb + ch * 16);
    }
  };

  stage(0, 0);
  stage(1, 1);
#pragma unroll 1
  for (int t = 0; t < NT; ++t) {
    // per-wave: own ds_reads (tile t-1) done; own A(t) share landed,
    // A(t+1) (newest 4 loads) may stay in flight.
    if (t + 1 < NT)
      asm volatile("s_waitcnt vmcnt(4) lgkmcnt(0)" ::: "memory");
    else
      asm volatile("s_waitcnt vmcnt(0) lgkmcnt(0)" ::: "memory");
    __builtin_amdgcn_s_barrier();     // raw barrier: no implicit vmcnt(0) drain
    __builtin_amdgcn_sched_barrier(0);
    // B pointer for this tile (global, packed chunk-major)
    const unsigned short* Bp;
    int ktl;
    if (FUSED) {
      const int ph = (t >= KT0) ? 1 : 0;
      Bp = ph ? B1 : B0;
      ktl = t - ph * KT0;
    } else {
      Bp = B0; ktl = t;
    }
    const unsigned short* Bbase = Bp + (size_t)ktl * (O * 64) + (size_t)(colb + wc * 64) * 8;
    // HOIST: issue all 8 B loads for this tile up front (oldest in queue)
    bf16x8 bg[4][2];
#pragma unroll
    for (int k16i = 0; k16i < 4; ++k16i) {
      const int c = k16i * 2 + fq;                  // chunk 0..7
#pragma unroll
      for (int cn = 0; cn < 2; ++cn)
        bg[k16i][cn] = *(const bf16x8*)(Bbase + (size_t)c * (O * 8) + (cn * 32 + fr) * 8);
    }
    if (t + 2 < NT) stage((t + 2) % 3, t + 2);      // overwrite buf read at t-1
    const char* lb = lds + (t % 3) * 16384;
#pragma unroll
    for (int k16i = 0; k16i < 4; ++k16i) {
      const int c = k16i * 2 + fq;                  // chunk 0..7
      bf16x8 af[2];
#pragma unroll
      for (int m = 0; m < 2; ++m) {
        const int rl = wr * 64 + m * 32 + fr;
        af[m] = *(const bf16x8*)(lb + rl * 128 + ((c ^ (rl & 7)) << 4));
      }
#pragma unroll
      for (int m = 0; m < 2; ++m)
#pragma unroll
        for (int cn = 0; cn < 2; ++cn)
          acc[m][cn] = __builtin_amdgcn_mfma_f32_32x32x16_bf16(af[m], bg[k16i][cn], acc[m][cn], 0, 0, 0);
    }
  }

  // epilogue. C/D map: col = lane&31, row = (reg&3) + 8*(reg>>2) + 4*(lane>>5).
#pragma unroll
  for (int cn = 0; cn < 2; ++cn) {
    const int col = colb + wc * 64 + cn * 32 + fr;
    float bb = 0.f;
    if (FUSED) bb = bias[col];
#pragma unroll
    for (int m = 0; m < 2; ++m) {
#pragma unroll
      for (int reg = 0; reg < 16; ++reg) {
        float v = acc[m][cn][reg];
        if (FUSED) v = fmaxf(v + bb, 0.f);
        const float nb = __shfl_xor(v, 1);
        const int row = row0 + m * 32 + (reg & 3) + 8 * (reg >> 2) + 4 * fq;
        if (!(lane & 1) && row < Nn) {
          *(unsigned int*)(C + (size_t)row * O + col) = packbf(v, nb);
        }
      }
    }
  }
}

// ---------------- head: logits(512->4) + softmax, 4 waves per block --------
// W4 (2048 f32 = 8KB) staged in LDS once per block.
__global__ __launch_bounds__(256)
void k_out_softmax(const unsigned short* __restrict__ h, const float* __restrict__ W4,
                   const float* __restrict__ b, float* __restrict__ out, int N) {
  __shared__ float w[2048];
  const int tid = threadIdx.x;
#pragma unroll
  for (int i = 0; i < 8; ++i) w[tid + i * 256] = W4[tid + i * 256];
  __syncthreads();
  const int n = blockIdx.x * 4 + (tid >> 6);
  if (n >= N) return;
  const int lane = tid & 63;
  const unsigned int* hp = (const unsigned int*)h + (size_t)n * 256;
  float a[4] = {0.f, 0.f, 0.f, 0.f};
#pragma unroll
  for (int it = 0; it < 4; ++it) {
    const unsigned int v = hp[it * 64 + lane];
    const float lo = lo16(v);
    const float hi = hi16(v);
    const int k = (it * 64 + lane) * 2;
#pragma unroll
    for (int c = 0; c < 4; ++c)
      a[c] += lo * w[c * 512 + k] + hi * w[c * 512 + k + 1];
  }
#pragma unroll
  for (int off = 32; off > 0; off >>= 1) {
#pragma unroll
    for (int c = 0; c < 4; ++c) a[c] += __shfl_down(a[c], off);
  }
  if (lane == 0) {
    const float l0 = a[0] + b[0], l1 = a[1] + b[1], l2 = a[2] + b[2], l3 = a[3] + b[3];
    const float m = fmaxf(fmaxf(l0, l1), fmaxf(l2, l3));
    const float e0 = expf(l0 - m), e1 = expf(l1 - m), e2 = expf(l2 - m), e3 = expf(l3 - m);
    const float inv = 1.0f / (e0 + e1 + e2 + e3);
    float4 r; r.x = e0 * inv; r.y = e1 * inv; r.z = e2 * inv; r.w = e3 * inv;
    *(float4*)(out + (size_t)n * 4) = r;
  }
}

// ---------------------------------------------------------------------------
extern "C" void kernel_launch(void* const* d_in, const int* in_sizes, int n_in,
                              void* d_out, int out_size, void* d_ws, size_t ws_size,
                              hipStream_t stream) {
  const float* x = (const float*)d_in[0];
  const float* Wl[5] = {(const float*)d_in[1], (const float*)d_in[4], (const float*)d_in[7],
                        (const float*)d_in[10], (const float*)d_in[13]};
  const float* bl[5] = {(const float*)d_in[2], (const float*)d_in[5], (const float*)d_in[8],
                        (const float*)d_in[11], (const float*)d_in[14]};
  const float* Wr[5] = {(const float*)d_in[3], (const float*)d_in[6], (const float*)d_in[9],
                        (const float*)d_in[12], (const float*)d_in[15]};
  const float* Wout = (const float*)d_in[16];
  const float* bout = (const float*)d_in[17];
  const int* eidx = (const int*)d_in[18];

  const int N = in_sizes[0] / 128;
  const int E = in_sizes[18] / 2;
  const int* srcI = eidx;
  const int* dstI = eidx + E;

  const int Kd[5] = {128, 128, 64, 128, 256};
  const int Od[5] = {128, 64, 128, 256, 512};

  // workspace carve-out (256B aligned)
  char* ws = (char*)d_ws;
  size_t p = 0;
  auto alloc = [&](size_t bytes) { size_t r = p; p += (bytes + 255) & ~(size_t)255; return r; };
  int*   deg     = (int*)(ws + alloc((size_t)N * 4));
  int*   row_off = (int*)(ws + alloc((size_t)(N + 1) * 4));
  int*   cursor  = (int*)(ws + alloc((size_t)N * 4));
  float* deg_inv = (float*)(ws + alloc((size_t)N * 4));
  int*   loc     = (int*)(ws + alloc((size_t)N * 4));
  int*   part    = (int*)(ws + alloc((size_t)1032 * 4));
  int*   esrc    = (int*)(ws + alloc((size_t)E * 4));
  unsigned short* xb = (unsigned short*)(ws + alloc((size_t)N * 128 * 2));
  unsigned short* wlb[5];
  unsigned short* wrb[5];
  for (int l = 0; l < 5; ++l) {
    wlb[l] = (unsigned short*)(ws + alloc((size_t)Od[l] * Kd[l] * 2));
    wrb[l] = (unsigned short*)(ws + alloc((size_t)Od[l] * Kd[l] * 2));
  }
  unsigned short* wcat1 = (unsigned short*)(ws + alloc((size_t)128 * 128 * 2));
  unsigned short* bufA = (unsigned short*)(ws + alloc((size_t)N * 512 * 2));
  unsigned short* bufB = (unsigned short*)(ws + alloc((size_t)N * 256 * 2));
  unsigned short* agg  = (unsigned short*)(ws + alloc((size_t)N * 256 * 2));
  (void)ws_size; (void)n_in; (void)out_size;

  // ---- conversions: x plain; weights packed chunk-major ----
  k_conv_x<<<128, 256, 0, stream>>>(x, xb, N * 128 / 4);
  PackJobs jobs;
  for (int l = 0; l < 5; ++l) {
    if (l == 1) {
      jobs.j[2] = {Wl[1], wcat1, 64, 128, 0, 128};   // Zl cols 0..63
      jobs.j[3] = {Wr[1], wcat1, 64, 128, 64, 128};  // Yr cols 64..127
    } else {
      jobs.j[2 * l]     = {Wl[l], wlb[l], Od[l], Kd[l], 0, Od[l]};
      jobs.j[2 * l + 1] = {Wr[l], wrb[l], Od[l], Kd[l], 0, Od[l]};
    }
  }
  k_pack_w<<<dim3(32, 10), 256, 0, stream>>>(jobs);

  // ---- CSR build (multi-block scan; x8-batched atomics) ----
  hipMemsetAsync(deg, 0, (size_t)N * 4, stream);
  k_count_deg<<<idiv_up(E, 2048), 256, 0, stream>>>(dstI, deg, E);
  const int nb = idiv_up(N, 1024);
  k_scan1<<<nb, 1024, 0, stream>>>(deg, loc, part, N);
  k_scan2<<<1, 1024, 0, stream>>>(part, nb);
  k_scan3<<<idiv_up(N + 1, 256), 256, 0, stream>>>(deg, loc, part, row_off, cursor, deg_inv, N, nb);
  k_fill_csr<<<idiv_up(E, 2048), 256, 0, stream>>>(srcI, dstI, cursor, esrc, E);

  const int gx8 = 8 * ((idiv_up(N, 128) + 7) / 8);   // padded row-panel grid

  // ---- layer 0: K=128, O=128 ----
  k_agg128<<<idiv_up(N, 4), 256, 0, stream>>>(xb, row_off, esrc, deg_inv, agg, N);
  k_sage_gemm<2, 1, true><<<gx8, 256, 0, stream>>>(agg, wlb[0], xb, wrb[0], bl[0], bufA, N, 128, 128);

  // ---- layer 1 (linearity swap): Z|Yr = h1 @ [Wl;Wr]^T, then fused agg ----
  k_sage_gemm<2, 1, false><<<gx8, 256, 0, stream>>>(bufA, wcat1, bufA, wcat1, bl[1], agg, N, 128, 128);
  k_agg_post64<<<idiv_up(N, 4), 256, 0, stream>>>(agg, row_off, esrc, deg_inv, bl[1], bufB, N);

  // ---- layer 2: K=64, O=128 ----
  k_agg64<<<idiv_up(N, 4), 256, 0, stream>>>(bufB, row_off, esrc, deg_inv, agg, N);
  k_sage_gemm<2, 1, true><<<gx8, 256, 0, stream>>>(agg, wlb[2], bufB, wrb[2], bl[2], bufA, N, 64, 128);

  // ---- layer 3: K=128, O=256 (2 col-blocks, XCD-co-located) ----
  k_agg128<<<idiv_up(N, 4), 256, 0, stream>>>(bufA, row_off, esrc, deg_inv, agg, N);
  k_sage_gemm<2, 2, true><<<2 * gx8, 256, 0, stream>>>(agg, wlb[3], bufA, wrb[3], bl[3], bufB, N, 128, 256);

  // ---- layer 4: K=256, O=512 (4 col-blocks, XCD-co-located) ----
  k_agg256<<<idiv_up(N, 4), 256, 0, stream>>>(bufB, row_off, esrc, deg_inv, agg, N);
  k_sage_gemm<2, 4, true><<<4 * gx8, 256, 0, stream>>>(agg, wlb[4], bufB, wrb[4], bl[4], bufA, N, 256, 512);

  k_out_softmax<<<idiv_up(N, 4), 256, 0, stream>>>(bufA, Wout, bout, (float*)d_out, N);
}